// Round 1
// baseline (522.824 us; speedup 1.0000x reference)
//
#include <hip/hip_runtime.h>
#include <hip/hip_bf16.h>
#include <math.h>

// MultiTaskGNN: 2-layer GAT + BN + ELU + two linear heads.
// N=50000, E=400000, DIN=256, L1: H=4,D=64 (concat 256), L2: H=1,D=64.
// All fp32 this round (correctness-first). Self-loops handled analytically
// (not materialized in CSR). Segment-max skipped: softmax shift-invariance +
// bounded |e| (<~5) makes plain exp fp32-safe; 1e-16 denom term negligible.

__device__ __forceinline__ float leaky02(float x) { return x >= 0.f ? x : 0.2f * x; }

__device__ __forceinline__ float wave_sum(float v) {
#pragma unroll
  for (int o = 1; o < 64; o <<= 1) v += __shfl_xor(v, o, 64);
  return v;
}

// ---------------- graph build ----------------
__global__ void zero_ints(int* p, int n) {
  int i = blockIdx.x * blockDim.x + threadIdx.x;
  if (i < n) p[i] = 0;
}

__global__ void hist_kernel(const int* __restrict__ dst, int* __restrict__ counts, int E) {
  int e = blockIdx.x * blockDim.x + threadIdx.x;
  if (e < E) atomicAdd(&counts[dst[e]], 1);
}

// single-block exclusive scan (N=50000 -> 49 chunk iterations)
__global__ void scan_kernel(const int* __restrict__ counts, int* __restrict__ offsets, int N) {
  __shared__ int lds[1024];
  int carry = 0;
  int chunks = (N + 1023) >> 10;
  for (int c = 0; c < chunks; ++c) {
    int i = (c << 10) + (int)threadIdx.x;
    int v = (i < N) ? counts[i] : 0;
    lds[threadIdx.x] = v;
    __syncthreads();
    for (int off = 1; off < 1024; off <<= 1) {
      int add = (threadIdx.x >= off) ? lds[threadIdx.x - off] : 0;
      __syncthreads();
      lds[threadIdx.x] += add;
      __syncthreads();
    }
    int incl = lds[threadIdx.x];
    if (i < N) offsets[i] = carry + (incl - v);
    carry += lds[1023];
    __syncthreads();
  }
  if (threadIdx.x == 0) offsets[N] = carry;
}

__global__ void scatter_kernel(const int* __restrict__ src, const int* __restrict__ dst,
                               const int* __restrict__ offsets, int* __restrict__ cursor,
                               int* __restrict__ csr_src, int E) {
  int e = blockIdx.x * blockDim.x + threadIdx.x;
  if (e < E) {
    int d = dst[e];
    int p = atomicAdd(&cursor[d], 1);
    csr_src[offsets[d] + p] = src[e];
  }
}

// ---------------- fp32 tiled GEMM: C[M,N] = A[M,K] @ B[K,N] ----------------
// 128x64 tile, 256 threads, 8x4 outputs/thread. N%64==0, K%16==0, M guarded.
__global__ __launch_bounds__(256) void gemm128x64(const float* __restrict__ A,
                                                  const float* __restrict__ B,
                                                  float* __restrict__ C,
                                                  int M, int N, int K) {
  __shared__ float As[16][128];  // [k][m]
  __shared__ float Bs[16][64];   // [k][n]
  const int t = threadIdx.x;
  const int tx = t & 15;   // 4 cols
  const int ty = t >> 4;   // 8 rows
  const int m0 = blockIdx.y * 128;
  const int n0 = blockIdx.x * 64;
  float acc[8][4];
#pragma unroll
  for (int i = 0; i < 8; ++i)
#pragma unroll
    for (int j = 0; j < 4; ++j) acc[i][j] = 0.f;

  const int ar0 = t >> 2;          // rows 0..63
  const int ar1 = ar0 + 64;        // rows 64..127
  const int ak = (t & 3) << 2;     // k offset 0/4/8/12
  const int br = t >> 4, bc = (t & 15) << 2;

  for (int k0 = 0; k0 < K; k0 += 16) {
    float4 a0 = make_float4(0.f, 0.f, 0.f, 0.f), a1 = a0;
    if (m0 + ar0 < M) a0 = *(const float4*)&A[(size_t)(m0 + ar0) * K + k0 + ak];
    if (m0 + ar1 < M) a1 = *(const float4*)&A[(size_t)(m0 + ar1) * K + k0 + ak];
    float4 bv = *(const float4*)&B[(size_t)(k0 + br) * N + n0 + bc];
    __syncthreads();
    As[ak + 0][ar0] = a0.x; As[ak + 1][ar0] = a0.y; As[ak + 2][ar0] = a0.z; As[ak + 3][ar0] = a0.w;
    As[ak + 0][ar1] = a1.x; As[ak + 1][ar1] = a1.y; As[ak + 2][ar1] = a1.z; As[ak + 3][ar1] = a1.w;
    *(float4*)&Bs[br][bc] = bv;
    __syncthreads();
#pragma unroll
    for (int k = 0; k < 16; ++k) {
      float4 av0 = *(const float4*)&As[k][ty * 8];
      float4 av1 = *(const float4*)&As[k][ty * 8 + 4];
      float4 b4 = *(const float4*)&Bs[k][tx * 4];
      float a[8] = {av0.x, av0.y, av0.z, av0.w, av1.x, av1.y, av1.z, av1.w};
      float b[4] = {b4.x, b4.y, b4.z, b4.w};
#pragma unroll
      for (int i = 0; i < 8; ++i)
#pragma unroll
        for (int j = 0; j < 4; ++j) acc[i][j] += a[i] * b[j];
    }
  }
#pragma unroll
  for (int i = 0; i < 8; ++i) {
    int m = m0 + ty * 8 + i;
    if (m < M) {
      float4 o = make_float4(acc[i][0], acc[i][1], acc[i][2], acc[i][3]);
      *(float4*)&C[(size_t)m * N + n0 + tx * 4] = o;
    }
  }
}

// ---------------- layer 1 alpha_s / alpha_d (per node, 4 heads) ----------------
__global__ __launch_bounds__(256) void alphas1_kernel(const float* __restrict__ h1,
                                                      const float* __restrict__ a_src,
                                                      const float* __restrict__ a_dst,
                                                      float* __restrict__ as_out,
                                                      float* __restrict__ ad_out, int N) {
  int n = blockIdx.x * 4 + (threadIdx.x >> 6);
  int lane = threadIdx.x & 63;
  if (n >= N) return;
  const float* row = h1 + (size_t)n * 256;
#pragma unroll
  for (int h = 0; h < 4; ++h) {
    float v = row[h * 64 + lane];
    float ps = wave_sum(v * a_src[h * 64 + lane]);
    float pd = wave_sum(v * a_dst[h * 64 + lane]);
    if (lane == 0) { as_out[n * 4 + h] = ps; ad_out[n * 4 + h] = pd; }
  }
}

// ---------------- layer 1 attention aggregation + bias + BN + ELU ----------------
__global__ __launch_bounds__(256) void agg1_kernel(
    const float* __restrict__ h1, const int* __restrict__ offsets,
    const int* __restrict__ csr_src, const float* __restrict__ as1,
    const float* __restrict__ ad1, const float* __restrict__ b1,
    const float* __restrict__ bn_w, const float* __restrict__ bn_b,
    const float* __restrict__ bn_m, const float* __restrict__ bn_v,
    float* __restrict__ out, int N) {
  int n = blockIdx.x * 4 + (threadIdx.x >> 6);
  int lane = threadIdx.x & 63;
  if (n >= N) return;
  int off = offsets[n], deg = offsets[n + 1] - off;
  float adv[4], acc[4] = {0, 0, 0, 0}, ds[4] = {0, 0, 0, 0};
#pragma unroll
  for (int h = 0; h < 4; ++h) adv[h] = ad1[n * 4 + h];

  for (int base = 0; base < deg; base += 64) {
    int sj = (base + lane < deg) ? csr_src[off + base + lane] : -1;
    float w[4] = {0, 0, 0, 0};
    if (sj >= 0) {
#pragma unroll
      for (int h = 0; h < 4; ++h) w[h] = __expf(leaky02(as1[sj * 4 + h] + adv[h]));
    }
#pragma unroll
    for (int h = 0; h < 4; ++h) ds[h] += w[h];
    int cnt = min(64, deg - base);
    for (int j = 0; j < cnt; ++j) {
      int s = __shfl(sj, j, 64);
      const float* hr = h1 + (size_t)s * 256;
#pragma unroll
      for (int h = 0; h < 4; ++h) {
        float wj = __shfl(w[h], j, 64);
        acc[h] += wj * hr[h * 64 + lane];
      }
    }
  }
  float den[4];
#pragma unroll
  for (int h = 0; h < 4; ++h) den[h] = wave_sum(ds[h]);
  // self loop
  const float* hn = h1 + (size_t)n * 256;
#pragma unroll
  for (int h = 0; h < 4; ++h) {
    float ws = __expf(leaky02(as1[n * 4 + h] + adv[h]));
    den[h] += ws;
    acc[h] += ws * hn[h * 64 + lane];
  }
#pragma unroll
  for (int h = 0; h < 4; ++h) {
    int c = h * 64 + lane;
    float o = acc[h] / (den[h] + 1e-16f) + b1[c];
    o = (o - bn_m[c]) * rsqrtf(bn_v[c] + 1e-5f) * bn_w[c] + bn_b[c];
    o = o > 0.f ? o : expm1f(o);  // ELU
    out[(size_t)n * 256 + c] = o;
  }
}

// ---------------- layer 2 alpha_s / alpha_d (per node, 1 head) ----------------
__global__ __launch_bounds__(256) void alphas2_kernel(const float* __restrict__ h2,
                                                      const float* __restrict__ a_src,
                                                      const float* __restrict__ a_dst,
                                                      float* __restrict__ as_out,
                                                      float* __restrict__ ad_out, int N) {
  int n = blockIdx.x * 4 + (threadIdx.x >> 6);
  int lane = threadIdx.x & 63;
  if (n >= N) return;
  float v = h2[(size_t)n * 64 + lane];
  float ps = wave_sum(v * a_src[lane]);
  float pd = wave_sum(v * a_dst[lane]);
  if (lane == 0) { as_out[n] = ps; ad_out[n] = pd; }
}

// ---------------- layer 2 agg + bias + BN + ELU + both heads ----------------
__global__ __launch_bounds__(256) void agg2_kernel(
    const float* __restrict__ h2, const int* __restrict__ offsets,
    const int* __restrict__ csr_src, const float* __restrict__ as2,
    const float* __restrict__ ad2, const float* __restrict__ b2,
    const float* __restrict__ bn_w, const float* __restrict__ bn_b,
    const float* __restrict__ bn_m, const float* __restrict__ bn_v,
    const float* __restrict__ Wr, const float* __restrict__ br,
    const float* __restrict__ Wc, const float* __restrict__ bc,
    float* __restrict__ out_reg, float* __restrict__ out_clf, int N) {
  int n = blockIdx.x * 4 + (threadIdx.x >> 6);
  int lane = threadIdx.x & 63;
  if (n >= N) return;
  int off = offsets[n], deg = offsets[n + 1] - off;
  float adv = ad2[n];
  float acc = 0.f, ds = 0.f;
  for (int base = 0; base < deg; base += 64) {
    int sj = (base + lane < deg) ? csr_src[off + base + lane] : -1;
    float w = (sj >= 0) ? __expf(leaky02(as2[sj] + adv)) : 0.f;
    ds += w;
    int cnt = min(64, deg - base);
    for (int j = 0; j < cnt; ++j) {
      int s = __shfl(sj, j, 64);
      float wj = __shfl(w, j, 64);
      acc += wj * h2[(size_t)s * 64 + lane];
    }
  }
  float den = wave_sum(ds);
  float ws = __expf(leaky02(as2[n] + adv));
  den += ws;
  acc += ws * h2[(size_t)n * 64 + lane];

  float o = acc / (den + 1e-16f) + b2[lane];
  o = (o - bn_m[lane]) * rsqrtf(bn_v[lane] + 1e-5f) * bn_w[lane] + bn_b[lane];
  o = o > 0.f ? o : expm1f(o);

  float rsum = wave_sum(o * Wr[lane]);
  float csum = wave_sum(o * Wc[lane]);
  if (lane == 0) {
    out_reg[n] = rsum + br[0];
    float z = csum + bc[0];
    out_clf[n] = 1.f / (1.f + __expf(-z));
  }
}

// ---------------- launcher ----------------
extern "C" void kernel_launch(void* const* d_in, const int* in_sizes, int n_in,
                              void* d_out, int out_size, void* d_ws, size_t ws_size,
                              hipStream_t stream) {
  const float* x      = (const float*)d_in[0];
  const int*   ei     = (const int*)d_in[1];
  const float* W1     = (const float*)d_in[2];
  const float* a_src1 = (const float*)d_in[3];
  const float* a_dst1 = (const float*)d_in[4];
  const float* b1     = (const float*)d_in[5];
  const float* bn1w   = (const float*)d_in[6];
  const float* bn1b   = (const float*)d_in[7];
  const float* bn1m   = (const float*)d_in[8];
  const float* bn1v   = (const float*)d_in[9];
  const float* W2     = (const float*)d_in[10];
  const float* a_src2 = (const float*)d_in[11];
  const float* a_dst2 = (const float*)d_in[12];
  const float* b2     = (const float*)d_in[13];
  const float* bn2w   = (const float*)d_in[14];
  const float* bn2b   = (const float*)d_in[15];
  const float* bn2m   = (const float*)d_in[16];
  const float* bn2v   = (const float*)d_in[17];
  const float* Wr     = (const float*)d_in[18];
  const float* br     = (const float*)d_in[19];
  const float* Wc     = (const float*)d_in[20];
  const float* bc     = (const float*)d_in[21];

  const int N = in_sizes[0] / 256;  // 50000
  const int E = in_sizes[1] / 2;    // 400000
  const int* srcv = ei;
  const int* dstv = ei + E;

  // workspace carve (256B aligned). Peak ~119 MB.
  char* w = (char*)d_ws;
  auto alloc = [&](size_t bytes) {
    char* p = w;
    w += (bytes + 255) & ~(size_t)255;
    return p;
  };
  int* counts   = (int*)alloc((size_t)N * 4);
  int* cursor   = (int*)alloc((size_t)N * 4);
  int* offsets  = (int*)alloc((size_t)(N + 1) * 4);
  int* csr_src  = (int*)alloc((size_t)E * 4);
  float* as1    = (float*)alloc((size_t)N * 4 * 4);
  float* ad1    = (float*)alloc((size_t)N * 4 * 4);
  float* as2    = (float*)alloc((size_t)N * 4);
  float* ad2    = (float*)alloc((size_t)N * 4);
  float* h1     = (float*)alloc((size_t)N * 256 * 4);
  float* h1act  = (float*)alloc((size_t)N * 256 * 4);
  float* h2     = (float*)alloc((size_t)N * 64 * 4);

  float* out_reg = (float*)d_out;

  // graph build (dst-CSR, self-loops handled analytically in agg kernels)
  zero_ints<<<(N + 255) / 256, 256, 0, stream>>>(counts, N);
  zero_ints<<<(N + 255) / 256, 256, 0, stream>>>(cursor, N);
  hist_kernel<<<(E + 255) / 256, 256, 0, stream>>>(dstv, counts, E);
  scan_kernel<<<1, 1024, 0, stream>>>(counts, offsets, N);
  scatter_kernel<<<(E + 255) / 256, 256, 0, stream>>>(srcv, dstv, offsets, cursor, csr_src, E);

  const int nwb = (N + 3) / 4;  // one wave per node, 4 waves/block

  // layer 1
  dim3 g1(256 / 64, (N + 127) / 128);
  gemm128x64<<<g1, 256, 0, stream>>>(x, W1, h1, N, 256, 256);
  alphas1_kernel<<<nwb, 256, 0, stream>>>(h1, a_src1, a_dst1, as1, ad1, N);
  agg1_kernel<<<nwb, 256, 0, stream>>>(h1, offsets, csr_src, as1, ad1, b1,
                                       bn1w, bn1b, bn1m, bn1v, h1act, N);

  // layer 2
  dim3 g2(1, (N + 127) / 128);
  gemm128x64<<<g2, 256, 0, stream>>>(h1act, W2, h2, N, 64, 256);
  alphas2_kernel<<<nwb, 256, 0, stream>>>(h2, a_src2, a_dst2, as2, ad2, N);
  agg2_kernel<<<nwb, 256, 0, stream>>>(h2, offsets, csr_src, as2, ad2, b2,
                                       bn2w, bn2b, bn2m, bn2v, Wr, br, Wc, bc,
                                       out_reg, out_reg + N, N);
}

// Round 2
// 359.875 us; speedup vs baseline: 1.4528x; 1.4528x over previous
//
#include <hip/hip_runtime.h>
#include <math.h>

// MultiTaskGNN: 2-layer GAT + BN + ELU + two heads. N=50000, E=400000.
// R2: bf16 MFMA GEMMs (16x16x32, verified frag layouts), hierarchical scan,
// bf16 head-interleaved h1 for the edge gather. fp32 accumulation throughout.

typedef unsigned short ushort_t;
typedef __attribute__((ext_vector_type(8))) unsigned short ushort8;
typedef __attribute__((ext_vector_type(8))) short short8;
typedef __attribute__((ext_vector_type(4))) float f32x4;

__device__ __forceinline__ ushort_t f2bf(float f) {  // RNE
  unsigned u = __float_as_uint(f);
  unsigned r = u + 0x7fffu + ((u >> 16) & 1u);
  return (ushort_t)(r >> 16);
}
__device__ __forceinline__ float bf2f(ushort_t h) {
  return __uint_as_float((unsigned)h << 16);
}
__device__ __forceinline__ float leaky02(float x) { return x >= 0.f ? x : 0.2f * x; }

__device__ __forceinline__ float wave_sum(float v) {
#pragma unroll
  for (int o = 1; o < 64; o <<= 1) v += __shfl_xor(v, o, 64);
  return v;
}
__device__ __forceinline__ int wave_incl_scan(int v, int lane) {
#pragma unroll
  for (int off = 1; off < 64; off <<= 1) {
    int t = __shfl_up(v, off, 64);
    if (lane >= off) v += t;
  }
  return v;
}

// ---------------- graph build ----------------
__global__ void zero_two(int* a, int* b, int n) {
  int i = blockIdx.x * blockDim.x + threadIdx.x;
  if (i < n) { a[i] = 0; b[i] = 0; }
}

__global__ void hist_kernel(const int* __restrict__ dst, int* __restrict__ counts, int E) {
  int e = blockIdx.x * blockDim.x + threadIdx.x;
  if (e < E) atomicAdd(&counts[dst[e]], 1);
}

__global__ __launch_bounds__(256) void scan_chunks_kernel(const int* __restrict__ counts,
                                                          int* __restrict__ offsets,
                                                          int* __restrict__ partials, int N) {
  __shared__ int ws[4];
  int tid = threadIdx.x, lane = tid & 63, wv = tid >> 6;
  int i = blockIdx.x * 256 + tid;
  int v = (i < N) ? counts[i] : 0;
  int incl = wave_incl_scan(v, lane);
  if (lane == 63) ws[wv] = incl;
  __syncthreads();
  int wbase = 0;
  for (int k = 0; k < wv; ++k) wbase += ws[k];
  if (i < N) offsets[i] = wbase + incl - v;
  if (tid == 255) partials[blockIdx.x] = wbase + incl;
}

__global__ __launch_bounds__(256) void scan_partials_kernel(const int* __restrict__ partials,
                                                            int* __restrict__ pprefix, int nb) {
  __shared__ int ws[4];
  int tid = threadIdx.x, lane = tid & 63, wv = tid >> 6;
  int v = (tid < nb) ? partials[tid] : 0;
  int incl = wave_incl_scan(v, lane);
  if (lane == 63) ws[wv] = incl;
  __syncthreads();
  int wbase = 0;
  for (int k = 0; k < wv; ++k) wbase += ws[k];
  if (tid < nb) pprefix[tid] = wbase + incl - v;
  if (tid == 255) pprefix[nb] = wbase + incl;  // grand total
}

__global__ void add_base_kernel(int* __restrict__ offsets, const int* __restrict__ pprefix,
                                int N, int nb) {
  int i = blockIdx.x * 256 + threadIdx.x;
  if (i < N) offsets[i] += pprefix[blockIdx.x];
  if (i == 0) offsets[N] = pprefix[nb];
}

__global__ void scatter_kernel(const int* __restrict__ src, const int* __restrict__ dst,
                               const int* __restrict__ offsets, int* __restrict__ cursor,
                               int* __restrict__ csr_src, int E) {
  int e = blockIdx.x * blockDim.x + threadIdx.x;
  if (e < E) {
    int d = dst[e];
    int p = atomicAdd(&cursor[d], 1);
    csr_src[offsets[d] + p] = src[e];
  }
}

// ---------------- bf16 casts ----------------
__global__ void cast_bf16_kernel(const float* __restrict__ in, ushort_t* __restrict__ out, int n4) {
  int i = blockIdx.x * blockDim.x + threadIdx.x;
  if (i < n4) {
    float4 v = ((const float4*)in)[i];
    ushort4 o;
    o.x = f2bf(v.x); o.y = f2bf(v.y); o.z = f2bf(v.z); o.w = f2bf(v.w);
    ((ushort4*)out)[i] = o;
  }
}

// Wt[n*K + k] = bf16(W[k*Ncols + n])
__global__ void transpose_cast_kernel(const float* __restrict__ W, ushort_t* __restrict__ Wt,
                                      int K, int Ncols) {
  int idx = blockIdx.x * 256 + threadIdx.x;
  if (idx < K * Ncols) {
    int k = idx / Ncols, n = idx % Ncols;
    Wt[n * K + k] = f2bf(W[idx]);
  }
}

// ---------------- MFMA bf16 GEMM: C[M,Nt] = A[M,K] @ Bt[Nt,K]^T ----------------
// BM=128, BN=64, BK=32; 256 threads = 4 waves, each wave 32x64 (2x4 16x16 tiles).
// OMODE: 0 = fp32 row-major out; 2 = bf16 head-interleaved out[m*256 + (col&63)*4 + (col>>6)]
template <int OMODE>
__global__ __launch_bounds__(256) void mfma_gemm_kernel(const ushort_t* __restrict__ A,
                                                        const ushort_t* __restrict__ Bt,
                                                        void* __restrict__ Cout,
                                                        int M, int Nt, int K) {
  __shared__ ushort_t As[128 * 32];
  __shared__ ushort_t Bs[64 * 32];
  const int t = threadIdx.x;
  const int w = t >> 6, l = t & 63;
  const int m0 = blockIdx.y * 128;
  const int n0 = blockIdx.x * 64;

  f32x4 zero4 = {0.f, 0.f, 0.f, 0.f};
  f32x4 acc[2][4];
#pragma unroll
  for (int i = 0; i < 2; ++i)
#pragma unroll
    for (int j = 0; j < 4; ++j) acc[i][j] = zero4;

  // staging map (fixed per thread)
  const int a_row = t >> 1;              // 0..127
  const int a_col = (t & 1) * 16;        // 0 or 16
  const int a_grow = min(m0 + a_row, M - 1);
  const int b_row = t >> 2;              // 0..63
  const int b_col = (t & 3) * 8;
  const ushort_t* Ag = A + (size_t)a_grow * K + a_col;
  const ushort_t* Bg = Bt + (size_t)(n0 + b_row) * K + b_col;
  ushort_t* AsW = &As[a_row * 32 + a_col];
  ushort_t* BsW = &Bs[b_row * 32 + b_col];

  for (int k0 = 0; k0 < K; k0 += 32) {
    ushort8 av0 = *(const ushort8*)(Ag + k0);
    ushort8 av1 = *(const ushort8*)(Ag + k0 + 8);
    ushort8 bv = *(const ushort8*)(Bg + k0);
    __syncthreads();  // previous iteration's LDS reads complete
    *(ushort8*)AsW = av0;
    *(ushort8*)(AsW + 8) = av1;
    *(ushort8*)BsW = bv;
    __syncthreads();
    const int kq = (l >> 4) * 8;
    short8 af[2], bfr[4];
#pragma unroll
    for (int i = 0; i < 2; ++i)
      af[i] = *(const short8*)&As[(w * 32 + i * 16 + (l & 15)) * 32 + kq];
#pragma unroll
    for (int j = 0; j < 4; ++j)
      bfr[j] = *(const short8*)&Bs[(j * 16 + (l & 15)) * 32 + kq];
#pragma unroll
    for (int i = 0; i < 2; ++i)
#pragma unroll
      for (int j = 0; j < 4; ++j)
        acc[i][j] = __builtin_amdgcn_mfma_f32_16x16x32_bf16(af[i], bfr[j], acc[i][j], 0, 0, 0);
  }

  const int rbase = m0 + w * 32 + (l >> 4) * 4;
  const int cbase = n0 + (l & 15);
#pragma unroll
  for (int i = 0; i < 2; ++i)
#pragma unroll
    for (int j = 0; j < 4; ++j)
#pragma unroll
      for (int r = 0; r < 4; ++r) {
        int row = rbase + i * 16 + r;
        int col = cbase + j * 16;
        if (row < M) {
          if (OMODE == 0) {
            ((float*)Cout)[(size_t)row * Nt + col] = acc[i][j][r];
          } else {
            // head-interleaved bf16: [m][d*4 + h], col = h*64 + d
            ((ushort_t*)Cout)[(size_t)row * 256 + (col & 63) * 4 + (col >> 6)] =
                f2bf(acc[i][j][r]);
          }
        }
      }
}

// ---------------- layer 1 alphas (h1 interleaved bf16) ----------------
__global__ __launch_bounds__(256) void alphas1_kernel(const ushort_t* __restrict__ h1i,
                                                      const float* __restrict__ a_src,
                                                      const float* __restrict__ a_dst,
                                                      float* __restrict__ as_out,
                                                      float* __restrict__ ad_out, int N) {
  int n = blockIdx.x * 4 + (threadIdx.x >> 6);
  int lane = threadIdx.x & 63;
  if (n >= N) return;
  ushort4 v4 = *(const ushort4*)&h1i[(size_t)n * 256 + lane * 4];
  float v[4] = {bf2f(v4.x), bf2f(v4.y), bf2f(v4.z), bf2f(v4.w)};
#pragma unroll
  for (int h = 0; h < 4; ++h) {
    float ps = wave_sum(v[h] * a_src[h * 64 + lane]);
    float pd = wave_sum(v[h] * a_dst[h * 64 + lane]);
    if (lane == 0) { as_out[n * 4 + h] = ps; ad_out[n * 4 + h] = pd; }
  }
}

// ---------------- layer 1 agg + bias + BN + ELU -> h1act (bf16, std layout) ----------------
__global__ __launch_bounds__(256) void agg1_kernel(
    const ushort_t* __restrict__ h1i, const int* __restrict__ offsets,
    const int* __restrict__ csr_src, const float* __restrict__ as1,
    const float* __restrict__ ad1, const float* __restrict__ b1,
    const float* __restrict__ bn_w, const float* __restrict__ bn_b,
    const float* __restrict__ bn_m, const float* __restrict__ bn_v,
    ushort_t* __restrict__ out, int N) {
  int n = blockIdx.x * 4 + (threadIdx.x >> 6);
  int lane = threadIdx.x & 63;
  if (n >= N) return;
  int off = offsets[n], deg = offsets[n + 1] - off;
  float4 advv = *(const float4*)&ad1[n * 4];
  float adv[4] = {advv.x, advv.y, advv.z, advv.w};
  float acc[4] = {0, 0, 0, 0}, ds[4] = {0, 0, 0, 0};

  for (int base = 0; base < deg; base += 64) {
    int sj = (base + lane < deg) ? csr_src[off + base + lane] : -1;
    float w[4] = {0, 0, 0, 0};
    if (sj >= 0) {
      float4 asv = *(const float4*)&as1[sj * 4];
      w[0] = __expf(leaky02(asv.x + adv[0]));
      w[1] = __expf(leaky02(asv.y + adv[1]));
      w[2] = __expf(leaky02(asv.z + adv[2]));
      w[3] = __expf(leaky02(asv.w + adv[3]));
    }
#pragma unroll
    for (int h = 0; h < 4; ++h) ds[h] += w[h];
    int cnt = min(64, deg - base);
    for (int j = 0; j < cnt; ++j) {
      int s = __shfl(sj, j, 64);
      ushort4 hv4 = *(const ushort4*)&h1i[(size_t)s * 256 + lane * 4];
      float hv[4] = {bf2f(hv4.x), bf2f(hv4.y), bf2f(hv4.z), bf2f(hv4.w)};
#pragma unroll
      for (int h = 0; h < 4; ++h) acc[h] += __shfl(w[h], j, 64) * hv[h];
    }
  }
  float den[4];
#pragma unroll
  for (int h = 0; h < 4; ++h) den[h] = wave_sum(ds[h]);
  // self loop
  ushort4 hn4 = *(const ushort4*)&h1i[(size_t)n * 256 + lane * 4];
  float hn[4] = {bf2f(hn4.x), bf2f(hn4.y), bf2f(hn4.z), bf2f(hn4.w)};
  float4 asn = *(const float4*)&as1[n * 4];
  float asnv[4] = {asn.x, asn.y, asn.z, asn.w};
#pragma unroll
  for (int h = 0; h < 4; ++h) {
    float ws = __expf(leaky02(asnv[h] + adv[h]));
    den[h] += ws;
    acc[h] += ws * hn[h];
  }
#pragma unroll
  for (int h = 0; h < 4; ++h) {
    int c = h * 64 + lane;
    float o = acc[h] / (den[h] + 1e-16f) + b1[c];
    o = (o - bn_m[c]) * rsqrtf(bn_v[c] + 1e-5f) * bn_w[c] + bn_b[c];
    o = o > 0.f ? o : expm1f(o);  // ELU
    out[(size_t)n * 256 + c] = f2bf(o);
  }
}

// ---------------- layer 2 alphas ----------------
__global__ __launch_bounds__(256) void alphas2_kernel(const float* __restrict__ h2,
                                                      const float* __restrict__ a_src,
                                                      const float* __restrict__ a_dst,
                                                      float* __restrict__ as_out,
                                                      float* __restrict__ ad_out, int N) {
  int n = blockIdx.x * 4 + (threadIdx.x >> 6);
  int lane = threadIdx.x & 63;
  if (n >= N) return;
  float v = h2[(size_t)n * 64 + lane];
  float ps = wave_sum(v * a_src[lane]);
  float pd = wave_sum(v * a_dst[lane]);
  if (lane == 0) { as_out[n] = ps; ad_out[n] = pd; }
}

// ---------------- layer 2 agg + BN + ELU + heads ----------------
__global__ __launch_bounds__(256) void agg2_kernel(
    const float* __restrict__ h2, const int* __restrict__ offsets,
    const int* __restrict__ csr_src, const float* __restrict__ as2,
    const float* __restrict__ ad2, const float* __restrict__ b2,
    const float* __restrict__ bn_w, const float* __restrict__ bn_b,
    const float* __restrict__ bn_m, const float* __restrict__ bn_v,
    const float* __restrict__ Wr, const float* __restrict__ br,
    const float* __restrict__ Wc, const float* __restrict__ bc,
    float* __restrict__ out_reg, float* __restrict__ out_clf, int N) {
  int n = blockIdx.x * 4 + (threadIdx.x >> 6);
  int lane = threadIdx.x & 63;
  if (n >= N) return;
  int off = offsets[n], deg = offsets[n + 1] - off;
  float adv = ad2[n];
  float acc = 0.f, ds = 0.f;
  for (int base = 0; base < deg; base += 64) {
    int sj = (base + lane < deg) ? csr_src[off + base + lane] : -1;
    float w = (sj >= 0) ? __expf(leaky02(as2[sj] + adv)) : 0.f;
    ds += w;
    int cnt = min(64, deg - base);
    for (int j = 0; j < cnt; ++j) {
      int s = __shfl(sj, j, 64);
      float wj = __shfl(w, j, 64);
      acc += wj * h2[(size_t)s * 64 + lane];
    }
  }
  float den = wave_sum(ds);
  float ws = __expf(leaky02(as2[n] + adv));
  den += ws;
  acc += ws * h2[(size_t)n * 64 + lane];

  float o = acc / (den + 1e-16f) + b2[lane];
  o = (o - bn_m[lane]) * rsqrtf(bn_v[lane] + 1e-5f) * bn_w[lane] + bn_b[lane];
  o = o > 0.f ? o : expm1f(o);

  float rsum = wave_sum(o * Wr[lane]);
  float csum = wave_sum(o * Wc[lane]);
  if (lane == 0) {
    out_reg[n] = rsum + br[0];
    float z = csum + bc[0];
    out_clf[n] = 1.f / (1.f + __expf(-z));
  }
}

// ---------------- launcher ----------------
extern "C" void kernel_launch(void* const* d_in, const int* in_sizes, int n_in,
                              void* d_out, int out_size, void* d_ws, size_t ws_size,
                              hipStream_t stream) {
  const float* x      = (const float*)d_in[0];
  const int*   ei     = (const int*)d_in[1];
  const float* W1     = (const float*)d_in[2];
  const float* a_src1 = (const float*)d_in[3];
  const float* a_dst1 = (const float*)d_in[4];
  const float* b1     = (const float*)d_in[5];
  const float* bn1w   = (const float*)d_in[6];
  const float* bn1b   = (const float*)d_in[7];
  const float* bn1m   = (const float*)d_in[8];
  const float* bn1v   = (const float*)d_in[9];
  const float* W2     = (const float*)d_in[10];
  const float* a_src2 = (const float*)d_in[11];
  const float* a_dst2 = (const float*)d_in[12];
  const float* b2     = (const float*)d_in[13];
  const float* bn2w   = (const float*)d_in[14];
  const float* bn2b   = (const float*)d_in[15];
  const float* bn2m   = (const float*)d_in[16];
  const float* bn2v   = (const float*)d_in[17];
  const float* Wr     = (const float*)d_in[18];
  const float* br     = (const float*)d_in[19];
  const float* Wc     = (const float*)d_in[20];
  const float* bc     = (const float*)d_in[21];

  const int N = in_sizes[0] / 256;  // 50000
  const int E = in_sizes[1] / 2;    // 400000
  const int* srcv = ei;
  const int* dstv = ei + E;

  char* w = (char*)d_ws;
  auto alloc = [&](size_t bytes) {
    char* p = w;
    w += (bytes + 255) & ~(size_t)255;
    return p;
  };
  const int nb = (N + 255) / 256;  // 196 scan chunks
  int* counts    = (int*)alloc((size_t)N * 4);
  int* cursor    = (int*)alloc((size_t)N * 4);
  int* offsets   = (int*)alloc((size_t)(N + 1) * 4);
  int* partials  = (int*)alloc((size_t)nb * 4);
  int* pprefix   = (int*)alloc((size_t)(nb + 1) * 4);
  int* csr_src   = (int*)alloc((size_t)E * 4);
  float* as1     = (float*)alloc((size_t)N * 4 * 4);
  float* ad1     = (float*)alloc((size_t)N * 4 * 4);
  float* as2     = (float*)alloc((size_t)N * 4);
  float* ad2     = (float*)alloc((size_t)N * 4);
  ushort_t* xb   = (ushort_t*)alloc((size_t)N * 256 * 2);
  ushort_t* W1t  = (ushort_t*)alloc((size_t)256 * 256 * 2);
  ushort_t* W2t  = (ushort_t*)alloc((size_t)64 * 256 * 2);
  ushort_t* h1i  = (ushort_t*)alloc((size_t)N * 256 * 2);  // interleaved [n][d*4+h]
  ushort_t* h1a  = (ushort_t*)alloc((size_t)N * 256 * 2);  // std layout [n][h*64+d]
  float* h2      = (float*)alloc((size_t)N * 64 * 4);

  float* out_reg = (float*)d_out;

  // graph build
  zero_two<<<(N + 255) / 256, 256, 0, stream>>>(counts, cursor, N);
  hist_kernel<<<(E + 255) / 256, 256, 0, stream>>>(dstv, counts, E);
  scan_chunks_kernel<<<nb, 256, 0, stream>>>(counts, offsets, partials, N);
  scan_partials_kernel<<<1, 256, 0, stream>>>(partials, pprefix, nb);
  add_base_kernel<<<nb, 256, 0, stream>>>(offsets, pprefix, N, nb);
  scatter_kernel<<<(E + 255) / 256, 256, 0, stream>>>(srcv, dstv, offsets, cursor, csr_src, E);

  // casts
  cast_bf16_kernel<<<(N * 256 / 4 + 255) / 256, 256, 0, stream>>>(x, xb, N * 256 / 4);
  transpose_cast_kernel<<<(256 * 256 + 255) / 256, 256, 0, stream>>>(W1, W1t, 256, 256);
  transpose_cast_kernel<<<(256 * 64 + 255) / 256, 256, 0, stream>>>(W2, W2t, 256, 64);

  const int nwb = (N + 3) / 4;  // one wave per node

  // layer 1
  dim3 g1(4, (N + 127) / 128);
  mfma_gemm_kernel<2><<<g1, 256, 0, stream>>>(xb, W1t, h1i, N, 256, 256);
  alphas1_kernel<<<nwb, 256, 0, stream>>>(h1i, a_src1, a_dst1, as1, ad1, N);
  agg1_kernel<<<nwb, 256, 0, stream>>>(h1i, offsets, csr_src, as1, ad1, b1,
                                       bn1w, bn1b, bn1m, bn1v, h1a, N);

  // layer 2
  dim3 g2(1, (N + 127) / 128);
  mfma_gemm_kernel<0><<<g2, 256, 0, stream>>>(h1a, W2t, h2, N, 64, 256);
  alphas2_kernel<<<nwb, 256, 0, stream>>>(h2, a_src2, a_dst2, as2, ad2, N);
  agg2_kernel<<<nwb, 256, 0, stream>>>(h2, offsets, csr_src, as2, ad2, b2,
                                       bn2w, bn2b, bn2m, bn2v, Wr, br, Wc, bc,
                                       out_reg, out_reg + N, N);
}

// Round 3
// 290.223 us; speedup vs baseline: 1.8015x; 1.2400x over previous
//
#include <hip/hip_runtime.h>
#include <math.h>

// MultiTaskGNN: 2-layer GAT + BN + ELU + two heads. N=50000, E=400000.
// R3: global_load_lds GEMM staging, alphas fused into GEMM epilogues,
// multi-edge-per-iteration pipelined aggregation, bf16 h2 path.

typedef unsigned short ushort_t;
typedef __attribute__((ext_vector_type(8))) unsigned short ushort8;
typedef __attribute__((ext_vector_type(4))) unsigned short ushort4v;
typedef __attribute__((ext_vector_type(8))) short short8;
typedef __attribute__((ext_vector_type(4))) float f32x4;

__device__ __forceinline__ ushort_t f2bf(float f) {  // RNE
  unsigned u = __float_as_uint(f);
  unsigned r = u + 0x7fffu + ((u >> 16) & 1u);
  return (ushort_t)(r >> 16);
}
__device__ __forceinline__ float bf2f(ushort_t h) {
  return __uint_as_float((unsigned)h << 16);
}
__device__ __forceinline__ float leaky02(float x) { return x >= 0.f ? x : 0.2f * x; }

__device__ __forceinline__ float wave_sum(float v) {
#pragma unroll
  for (int o = 1; o < 64; o <<= 1) v += __shfl_xor(v, o, 64);
  return v;
}
__device__ __forceinline__ int wave_incl_scan(int v, int lane) {
#pragma unroll
  for (int off = 1; off < 64; off <<= 1) {
    int t = __shfl_up(v, off, 64);
    if (lane >= off) v += t;
  }
  return v;
}

__device__ __forceinline__ void gld_lds16(const ushort_t* g, ushort_t* l) {
  __builtin_amdgcn_global_load_lds(
      (const __attribute__((address_space(1))) unsigned int*)g,
      (__attribute__((address_space(3))) unsigned int*)l, 16, 0, 0);
}

// ---------------- graph build ----------------
__global__ void zero_two(int* a, int* b, int n) {
  int i = blockIdx.x * blockDim.x + threadIdx.x;
  if (i < n) { a[i] = 0; b[i] = 0; }
}

__global__ void hist_kernel(const int* __restrict__ dst, int* __restrict__ counts, int E) {
  int e = blockIdx.x * blockDim.x + threadIdx.x;
  if (e < E) atomicAdd(&counts[dst[e]], 1);
}

__global__ __launch_bounds__(256) void scan_chunks_kernel(const int* __restrict__ counts,
                                                          int* __restrict__ offsets,
                                                          int* __restrict__ partials, int N) {
  __shared__ int ws[4];
  int tid = threadIdx.x, lane = tid & 63, wv = tid >> 6;
  int i = blockIdx.x * 256 + tid;
  int v = (i < N) ? counts[i] : 0;
  int incl = wave_incl_scan(v, lane);
  if (lane == 63) ws[wv] = incl;
  __syncthreads();
  int wbase = 0;
  for (int k = 0; k < wv; ++k) wbase += ws[k];
  if (i < N) offsets[i] = wbase + incl - v;
  if (tid == 255) partials[blockIdx.x] = wbase + incl;
}

__global__ __launch_bounds__(256) void scan_partials_kernel(const int* __restrict__ partials,
                                                            int* __restrict__ pprefix, int nb) {
  __shared__ int ws[4];
  int tid = threadIdx.x, lane = tid & 63, wv = tid >> 6;
  int v = (tid < nb) ? partials[tid] : 0;
  int incl = wave_incl_scan(v, lane);
  if (lane == 63) ws[wv] = incl;
  __syncthreads();
  int wbase = 0;
  for (int k = 0; k < wv; ++k) wbase += ws[k];
  if (tid < nb) pprefix[tid] = wbase + incl - v;
  if (tid == 255) pprefix[nb] = wbase + incl;
}

__global__ void add_base_kernel(int* __restrict__ offsets, const int* __restrict__ pprefix,
                                int N, int nb) {
  int i = blockIdx.x * 256 + threadIdx.x;
  if (i < N) offsets[i] += pprefix[blockIdx.x];
  if (i == 0) offsets[N] = pprefix[nb];
}

__global__ void scatter_kernel(const int* __restrict__ src, const int* __restrict__ dst,
                               const int* __restrict__ offsets, int* __restrict__ cursor,
                               int* __restrict__ csr_src, int E) {
  int e = blockIdx.x * blockDim.x + threadIdx.x;
  if (e < E) {
    int d = dst[e];
    int p = atomicAdd(&cursor[d], 1);
    csr_src[offsets[d] + p] = src[e];
  }
}

// ---------------- casts ----------------
__global__ void cast_bf16_kernel(const float* __restrict__ in, ushort_t* __restrict__ out, int n4) {
  int i = blockIdx.x * blockDim.x + threadIdx.x;
  if (i < n4) {
    float4 v = ((const float4*)in)[i];
    ushort4 o;
    o.x = f2bf(v.x); o.y = f2bf(v.y); o.z = f2bf(v.z); o.w = f2bf(v.w);
    ((ushort4*)out)[i] = o;
  }
}

// both weight transposes in one dispatch: Wt[n][k] = bf16(W[k][n])
__global__ void prep_weights_kernel(const float* __restrict__ W1, const float* __restrict__ W2,
                                    ushort_t* __restrict__ W1t, ushort_t* __restrict__ W2t) {
  int i = blockIdx.x * 256 + threadIdx.x;
  if (i < 256 * 256) {
    int k = i >> 8, n2 = i & 255;
    W1t[n2 * 256 + k] = f2bf(W1[i]);
  } else {
    int j = i - 256 * 256;
    if (j < 256 * 64) {
      int k = j >> 6, n2 = j & 63;
      W2t[n2 * 256 + k] = f2bf(W2[j]);
    }
  }
}

// ---------------- MFMA bf16 GEMM + fused alpha epilogue ----------------
// C[M,Nt] = A[M,K] @ Bt[Nt,K]^T, bf16 out (std row-major).
// WM waves, BM=32*WM rows, 64 cols/block (= one attention head's columns).
// Epilogue also computes as_out[row*H+head] = sum_d C[row,head*64+d]*avs[head*64+d], same for avd.
template <int WM>
__global__ __launch_bounds__(WM * 64) void mfma_gemm_fused(
    const ushort_t* __restrict__ A, const ushort_t* __restrict__ Bt,
    ushort_t* __restrict__ C, const float* __restrict__ avs, const float* __restrict__ avd,
    float* __restrict__ as_out, float* __restrict__ ad_out, int M, int Nt, int K, int H) {
  constexpr int BM = WM * 32;
  constexpr int NB = 4 / WM;  // B staging insts per wave
  __shared__ ushort_t As[BM * 32];
  __shared__ ushort_t Bs[64 * 32];
  const int t = threadIdx.x;
  const int w = t >> 6, l = t & 63;
  const int m0 = blockIdx.y * BM;
  const int n0 = blockIdx.x * 64;
  const int head = n0 >> 6;

  f32x4 zero4 = {0.f, 0.f, 0.f, 0.f};
  f32x4 acc[2][4];
#pragma unroll
  for (int i = 0; i < 2; ++i)
#pragma unroll
    for (int j = 0; j < 4; ++j) acc[i][j] = zero4;

  // staging maps: each wave-inst covers 1 KB = 16 rows x 32 cols bf16,
  // lane covers row base+ (l>>2), col (l&3)*8; LDS dest = base + lane*16B.
  const int scol = (l & 3) * 8;
  const ushort_t* Aga[2];
  ushort_t* Asl[2];
#pragma unroll
  for (int a = 0; a < 2; ++a) {
    int r = (a * WM + w) * 16 + (l >> 2);
    int gr = min(m0 + r, M - 1);
    Aga[a] = A + (size_t)gr * K + scol;
    Asl[a] = &As[(a * WM + w) * 512];
  }
  const ushort_t* Bgb[NB];
  ushort_t* Bsl[NB];
#pragma unroll
  for (int b = 0; b < NB; ++b) {
    int r = (b * WM + w) * 16 + (l >> 2);
    Bgb[b] = Bt + (size_t)(n0 + r) * K + scol;
    Bsl[b] = &Bs[(b * WM + w) * 512];
  }

  for (int k0 = 0; k0 < K; k0 += 32) {
    __syncthreads();  // previous iter's frag reads done
#pragma unroll
    for (int a = 0; a < 2; ++a) gld_lds16(Aga[a] + k0, Asl[a]);
#pragma unroll
    for (int b = 0; b < NB; ++b) gld_lds16(Bgb[b] + k0, Bsl[b]);
    __syncthreads();  // drains vmcnt -> LDS visible
    const int kq = (l >> 4) * 8;
    short8 af[2], bfr[4];
#pragma unroll
    for (int i = 0; i < 2; ++i)
      af[i] = *(const short8*)&As[(w * 32 + i * 16 + (l & 15)) * 32 + kq];
#pragma unroll
    for (int j = 0; j < 4; ++j)
      bfr[j] = *(const short8*)&Bs[(j * 16 + (l & 15)) * 32 + kq];
#pragma unroll
    for (int i = 0; i < 2; ++i)
#pragma unroll
      for (int j = 0; j < 4; ++j)
        acc[i][j] = __builtin_amdgcn_mfma_f32_16x16x32_bf16(af[i], bfr[j], acc[i][j], 0, 0, 0);
  }

  // C store (bf16 std row-major; 16-lane groups write 32B-contiguous segments)
  const int rbase = m0 + w * 32 + (l >> 4) * 4;
  const int cbase = n0 + (l & 15);
#pragma unroll
  for (int i = 0; i < 2; ++i)
#pragma unroll
    for (int j = 0; j < 4; ++j)
#pragma unroll
      for (int r = 0; r < 4; ++r) {
        int row = rbase + i * 16 + r;
        if (row < M) C[(size_t)row * Nt + cbase + j * 16] = f2bf(acc[i][j][r]);
      }

  // fused alphas: per-row dot with a_src/a_dst over this head's 64 cols
  float asw[4], adw[4];
#pragma unroll
  for (int j = 0; j < 4; ++j) {
    asw[j] = avs[head * 64 + (l & 15) + j * 16];
    adw[j] = avd[head * 64 + (l & 15) + j * 16];
  }
#pragma unroll
  for (int i = 0; i < 2; ++i)
#pragma unroll
    for (int r = 0; r < 4; ++r) {
      float s_ = acc[i][0][r] * asw[0] + acc[i][1][r] * asw[1] +
                 acc[i][2][r] * asw[2] + acc[i][3][r] * asw[3];
      float d_ = acc[i][0][r] * adw[0] + acc[i][1][r] * adw[1] +
                 acc[i][2][r] * adw[2] + acc[i][3][r] * adw[3];
#pragma unroll
      for (int o = 1; o < 16; o <<= 1) {
        s_ += __shfl_xor(s_, o, 64);
        d_ += __shfl_xor(d_, o, 64);
      }
      if ((l & 15) == 0) {
        int row = rbase + i * 16 + r;
        if (row < M) {
          as_out[(size_t)row * H + head] = s_;
          ad_out[(size_t)row * H + head] = d_;
        }
      }
    }
}

// ---------------- layer 1 agg: 2 edges/iter, pipelined; bf16 in/out ----------------
__global__ __launch_bounds__(256) void agg1_kernel(
    const ushort_t* __restrict__ h1, const int* __restrict__ offsets,
    const int* __restrict__ csr, const float* __restrict__ as1,
    const float* __restrict__ ad1, const float* __restrict__ b1,
    const float* __restrict__ bnw, const float* __restrict__ bnb,
    const float* __restrict__ bnm, const float* __restrict__ bnv,
    ushort_t* __restrict__ out, int N) {
  int n = blockIdx.x * 4 + (threadIdx.x >> 6);
  int l = threadIdx.x & 63;
  if (n >= N) return;
  const int g = l >> 5, ll = l & 31;  // features f = ll*8..+7, all in head hh
  const int hh = ll >> 3;
  int off = offsets[n], deg = offsets[n + 1] - off;
  float4 ad4 = *(const float4*)&ad1[n * 4];
  float adv[4] = {ad4.x, ad4.y, ad4.z, ad4.w};
  float acc[8] = {0, 0, 0, 0, 0, 0, 0, 0};
  float ds[4] = {0, 0, 0, 0};

  for (int base = 0; base < deg; base += 64) {
    bool inb = base + l < deg;
    int sj = inb ? csr[off + base + l] : 0;
    float w0 = 0.f, w1 = 0.f, w2 = 0.f, w3 = 0.f;
    if (inb) {
      float4 a4 = *(const float4*)&as1[sj * 4];
      w0 = __expf(leaky02(a4.x + adv[0]));
      w1 = __expf(leaky02(a4.y + adv[1]));
      w2 = __expf(leaky02(a4.z + adv[2]));
      w3 = __expf(leaky02(a4.w + adv[3]));
    }
    ds[0] += w0; ds[1] += w1; ds[2] += w2; ds[3] += w3;
    int cnt = min(64, deg - base);
    // software-pipelined: group g handles edge j+g
    int sl0 = min(g, cnt - 1);
    int s_c = __shfl(sj, sl0, 64);
    float a0 = __shfl(w0, sl0, 64), a1 = __shfl(w1, sl0, 64),
          a2 = __shfl(w2, sl0, 64), a3 = __shfl(w3, sl0, 64);
    float lo = (hh & 1) ? a1 : a0, hi = (hh & 1) ? a3 : a2;
    float w_c = (hh & 2) ? hi : lo;
    if (g >= cnt) w_c = 0.f;
    ushort8 hv_c = *(const ushort8*)&h1[(size_t)s_c * 256 + ll * 8];
    for (int j = 2; j < cnt; j += 2) {
      int sl1 = min(j + g, cnt - 1);
      int s_n = __shfl(sj, sl1, 64);
      float b0 = __shfl(w0, sl1, 64), b1_ = __shfl(w1, sl1, 64),
            b2_ = __shfl(w2, sl1, 64), b3 = __shfl(w3, sl1, 64);
      float nlo = (hh & 1) ? b1_ : b0, nhi = (hh & 1) ? b3 : b2_;
      float w_n = (hh & 2) ? nhi : nlo;
      if (j + g >= cnt) w_n = 0.f;
      ushort8 hv_n = *(const ushort8*)&h1[(size_t)s_n * 256 + ll * 8];
#pragma unroll
      for (int k = 0; k < 8; ++k) acc[k] = fmaf(w_c, bf2f(hv_c[k]), acc[k]);
      w_c = w_n; hv_c = hv_n;
    }
#pragma unroll
    for (int k = 0; k < 8; ++k) acc[k] = fmaf(w_c, bf2f(hv_c[k]), acc[k]);
  }
  // cross-group reduce
#pragma unroll
  for (int k = 0; k < 8; ++k) acc[k] += __shfl_xor(acc[k], 32, 64);
  float den[4];
#pragma unroll
  for (int h = 0; h < 4; ++h) den[h] = wave_sum(ds[h]);
  // self loop
  float4 asn4 = *(const float4*)&as1[n * 4];
  float asn[4] = {asn4.x, asn4.y, asn4.z, asn4.w};
  float wsf[4];
#pragma unroll
  for (int h = 0; h < 4; ++h) {
    wsf[h] = __expf(leaky02(asn[h] + adv[h]));
    den[h] += wsf[h];
  }
  ushort8 hvn = *(const ushort8*)&h1[(size_t)n * 256 + ll * 8];
  float wsh = wsf[hh];
#pragma unroll
  for (int k = 0; k < 8; ++k) acc[k] = fmaf(wsh, bf2f(hvn[k]), acc[k]);
  // BN + ELU + store own 4-feature half (group g -> k = g*4..g*4+3)
  float inv_den = 1.f / (den[hh] + 1e-16f);
  int c0 = ll * 8 + g * 4;
  float4 bb = *(const float4*)&b1[c0];
  float4 bw = *(const float4*)&bnw[c0];
  float4 bbb = *(const float4*)&bnb[c0];
  float4 bm = *(const float4*)&bnm[c0];
  float4 bv = *(const float4*)&bnv[c0];
  float bbf[4] = {bb.x, bb.y, bb.z, bb.w};
  float bwf[4] = {bw.x, bw.y, bw.z, bw.w};
  float bbbf[4] = {bbb.x, bbb.y, bbb.z, bbb.w};
  float bmf[4] = {bm.x, bm.y, bm.z, bm.w};
  float bvf[4] = {bv.x, bv.y, bv.z, bv.w};
  ushort4v o4;
#pragma unroll
  for (int q = 0; q < 4; ++q) {
    float o = acc[g * 4 + q] * inv_den + bbf[q];
    o = (o - bmf[q]) * rsqrtf(bvf[q] + 1e-5f) * bwf[q] + bbbf[q];
    o = o > 0.f ? o : expm1f(o);
    o4[q] = f2bf(o);
  }
  *(ushort4v*)&out[(size_t)n * 256 + c0] = o4;
}

// ---------------- layer 2 agg: 4 edges/iter, pipelined; bf16 h2; fused heads ----------------
__global__ __launch_bounds__(256) void agg2_kernel(
    const ushort_t* __restrict__ h2, const int* __restrict__ offsets,
    const int* __restrict__ csr, const float* __restrict__ as2,
    const float* __restrict__ ad2, const float* __restrict__ b2,
    const float* __restrict__ bnw, const float* __restrict__ bnb,
    const float* __restrict__ bnm, const float* __restrict__ bnv,
    const float* __restrict__ Wr, const float* __restrict__ br,
    const float* __restrict__ Wc, const float* __restrict__ bc,
    float* __restrict__ out_reg, float* __restrict__ out_clf, int N) {
  int n = blockIdx.x * 4 + (threadIdx.x >> 6);
  int l = threadIdx.x & 63;
  if (n >= N) return;
  const int g = l >> 4, ll = l & 15;  // features d = ll*4..+3
  int off = offsets[n], deg = offsets[n + 1] - off;
  float adv = ad2[n];
  float acc[4] = {0, 0, 0, 0};
  float ds = 0.f;

  for (int base = 0; base < deg; base += 64) {
    bool inb = base + l < deg;
    int sj = inb ? csr[off + base + l] : 0;
    float w = inb ? __expf(leaky02(as2[sj] + adv)) : 0.f;
    ds += w;
    int cnt = min(64, deg - base);
    int sl0 = min(g, cnt - 1);
    int s_c = __shfl(sj, sl0, 64);
    float w_c = __shfl(w, sl0, 64);
    if (g >= cnt) w_c = 0.f;
    ushort4v hv_c = *(const ushort4v*)&h2[(size_t)s_c * 64 + ll * 4];
    for (int j = 4; j < cnt; j += 4) {
      int sl1 = min(j + g, cnt - 1);
      int s_n = __shfl(sj, sl1, 64);
      float w_n = __shfl(w, sl1, 64);
      if (j + g >= cnt) w_n = 0.f;
      ushort4v hv_n = *(const ushort4v*)&h2[(size_t)s_n * 64 + ll * 4];
#pragma unroll
      for (int k = 0; k < 4; ++k) acc[k] = fmaf(w_c, bf2f(hv_c[k]), acc[k]);
      w_c = w_n; hv_c = hv_n;
    }
#pragma unroll
    for (int k = 0; k < 4; ++k) acc[k] = fmaf(w_c, bf2f(hv_c[k]), acc[k]);
  }
  // cross-group reduce (4 dup groups after both steps)
#pragma unroll
  for (int k = 0; k < 4; ++k) {
    acc[k] += __shfl_xor(acc[k], 16, 64);
    acc[k] += __shfl_xor(acc[k], 32, 64);
  }
  float den = wave_sum(ds);
  float ws = __expf(leaky02(as2[n] + adv));
  den += ws;
  ushort4v hvn = *(const ushort4v*)&h2[(size_t)n * 64 + ll * 4];
#pragma unroll
  for (int k = 0; k < 4; ++k) acc[k] = fmaf(ws, bf2f(hvn[k]), acc[k]);

  float inv_den = 1.f / (den + 1e-16f);
  int c0 = ll * 4;
  float4 bb = *(const float4*)&b2[c0];
  float4 bw = *(const float4*)&bnw[c0];
  float4 bbb = *(const float4*)&bnb[c0];
  float4 bm = *(const float4*)&bnm[c0];
  float4 bv = *(const float4*)&bnv[c0];
  float4 wr = *(const float4*)&Wr[c0];
  float4 wc = *(const float4*)&Wc[c0];
  float bbf[4] = {bb.x, bb.y, bb.z, bb.w};
  float bwf[4] = {bw.x, bw.y, bw.z, bw.w};
  float bbbf[4] = {bbb.x, bbb.y, bbb.z, bbb.w};
  float bmf[4] = {bm.x, bm.y, bm.z, bm.w};
  float bvf[4] = {bv.x, bv.y, bv.z, bv.w};
  float wrf[4] = {wr.x, wr.y, wr.z, wr.w};
  float wcf[4] = {wc.x, wc.y, wc.z, wc.w};
  float rs = 0.f, cs = 0.f;
#pragma unroll
  for (int q = 0; q < 4; ++q) {
    float o = acc[q] * inv_den + bbf[q];
    o = (o - bmf[q]) * rsqrtf(bvf[q] + 1e-5f) * bwf[q] + bbbf[q];
    o = o > 0.f ? o : expm1f(o);
    rs = fmaf(o, wrf[q], rs);
    cs = fmaf(o, wcf[q], cs);
  }
  // each feature appears in 4 duplicate lane-groups -> wave_sum gives 4x
  float rsum = wave_sum(rs) * 0.25f;
  float csum = wave_sum(cs) * 0.25f;
  if (l == 0) {
    out_reg[n] = rsum + br[0];
    float z = csum + bc[0];
    out_clf[n] = 1.f / (1.f + __expf(-z));
  }
}

// ---------------- launcher ----------------
extern "C" void kernel_launch(void* const* d_in, const int* in_sizes, int n_in,
                              void* d_out, int out_size, void* d_ws, size_t ws_size,
                              hipStream_t stream) {
  const float* x      = (const float*)d_in[0];
  const int*   ei     = (const int*)d_in[1];
  const float* W1     = (const float*)d_in[2];
  const float* a_src1 = (const float*)d_in[3];
  const float* a_dst1 = (const float*)d_in[4];
  const float* b1     = (const float*)d_in[5];
  const float* bn1w   = (const float*)d_in[6];
  const float* bn1b   = (const float*)d_in[7];
  const float* bn1m   = (const float*)d_in[8];
  const float* bn1v   = (const float*)d_in[9];
  const float* W2     = (const float*)d_in[10];
  const float* a_src2 = (const float*)d_in[11];
  const float* a_dst2 = (const float*)d_in[12];
  const float* b2     = (const float*)d_in[13];
  const float* bn2w   = (const float*)d_in[14];
  const float* bn2b   = (const float*)d_in[15];
  const float* bn2m   = (const float*)d_in[16];
  const float* bn2v   = (const float*)d_in[17];
  const float* Wr     = (const float*)d_in[18];
  const float* br     = (const float*)d_in[19];
  const float* Wc     = (const float*)d_in[20];
  const float* bc     = (const float*)d_in[21];

  const int N = in_sizes[0] / 256;  // 50000
  const int E = in_sizes[1] / 2;    // 400000
  const int* srcv = ei;
  const int* dstv = ei + E;

  char* w = (char*)d_ws;
  auto alloc = [&](size_t bytes) {
    char* p = w;
    w += (bytes + 255) & ~(size_t)255;
    return p;
  };
  const int nb = (N + 255) / 256;
  int* counts    = (int*)alloc((size_t)N * 4);
  int* cursor    = (int*)alloc((size_t)N * 4);
  int* offsets   = (int*)alloc((size_t)(N + 1) * 4);
  int* partials  = (int*)alloc((size_t)nb * 4);
  int* pprefix   = (int*)alloc((size_t)(nb + 1) * 4);
  int* csr_src   = (int*)alloc((size_t)E * 4);
  float* as1     = (float*)alloc((size_t)N * 4 * 4);
  float* ad1     = (float*)alloc((size_t)N * 4 * 4);
  float* as2     = (float*)alloc((size_t)N * 4);
  float* ad2     = (float*)alloc((size_t)N * 4);
  ushort_t* xb   = (ushort_t*)alloc((size_t)N * 256 * 2);
  ushort_t* W1t  = (ushort_t*)alloc((size_t)256 * 256 * 2);
  ushort_t* W2t  = (ushort_t*)alloc((size_t)64 * 256 * 2);
  ushort_t* h1b  = (ushort_t*)alloc((size_t)N * 256 * 2);  // gemm1 out, std layout
  ushort_t* h1a  = (ushort_t*)alloc((size_t)N * 256 * 2);  // agg1 out
  ushort_t* h2b  = (ushort_t*)alloc((size_t)N * 64 * 2);   // gemm2 out

  float* out_reg = (float*)d_out;

  // graph build
  zero_two<<<(N + 255) / 256, 256, 0, stream>>>(counts, cursor, N);
  hist_kernel<<<(E + 255) / 256, 256, 0, stream>>>(dstv, counts, E);
  scan_chunks_kernel<<<nb, 256, 0, stream>>>(counts, offsets, partials, N);
  scan_partials_kernel<<<1, 256, 0, stream>>>(partials, pprefix, nb);
  add_base_kernel<<<nb, 256, 0, stream>>>(offsets, pprefix, N, nb);
  scatter_kernel<<<(E + 255) / 256, 256, 0, stream>>>(srcv, dstv, offsets, cursor, csr_src, E);

  // casts
  cast_bf16_kernel<<<(N * 256 / 4 + 255) / 256, 256, 0, stream>>>(x, xb, N * 256 / 4);
  prep_weights_kernel<<<(256 * 256 + 256 * 64 + 255) / 256, 256, 0, stream>>>(W1, W2, W1t, W2t);

  const int nwb = (N + 3) / 4;

  // layer 1: GEMM (+alphas fused) then agg
  dim3 g1(4, (N + 127) / 128);
  mfma_gemm_fused<4><<<g1, 256, 0, stream>>>(xb, W1t, h1b, a_src1, a_dst1, as1, ad1,
                                             N, 256, 256, 4);
  agg1_kernel<<<nwb, 256, 0, stream>>>(h1b, offsets, csr_src, as1, ad1, b1,
                                       bn1w, bn1b, bn1m, bn1v, h1a, N);

  // layer 2: GEMM (+alphas fused) then agg + heads
  dim3 g2(1, (N + 63) / 64);
  mfma_gemm_fused<2><<<g2, 128, 0, stream>>>(h1a, W2t, h2b, a_src2, a_dst2, as2, ad2,
                                             N, 64, 256, 1);
  agg2_kernel<<<nwb, 256, 0, stream>>>(h2b, offsets, csr_src, as2, ad2, b2,
                                       bn2w, bn2b, bn2m, bn2v, Wr, br, Wc, bc,
                                       out_reg, out_reg + N, N);
}